// Round 13
// baseline (206.914 us; speedup 1.0000x reference)
//
#include <hip/hip_runtime.h>
#include <math.h>

#define NPTS 4096
#define MPTS 4096
#define NSTEPS 8
#define ICP_TOL 1e-6f
#define NBLK 512    // 512 blocks x 512 threads = 2 blocks/CU, 4 waves/SIMD
#define NSUB 32     // arrival sub-counters, 16 blocks each

// ws layout (floats):
//   ptgt4 : [0, 32768)         interleaved {x,y,z,0.5*|t|^2}, 2*4096 targets
//   acc   : [32768, 98304)     [step][block(512)][16] per-block partials (atomic stores)
//   ctrs  : words at 98304, 1536/step: subs at c*16 (c<32), master at 512,
//           flags at 1024+f*16 (f<32); value 0=wait, 1=continue, 2=done
//   stpub : floats at 110592, 32/step: [step][batch][16] published R(9)+t(3)
#define ACC_OFF 32768
#define CTR_OFF 98304
#define CTR_STRIDE 1536
#define STPUB_OFF 110592

__global__ void init_kernel(const float* __restrict__ ptgt, float* __restrict__ ws) {
    float* ptgt4 = ws;
    unsigned* ctrs = (unsigned*)(ws + CTR_OFF);
    int gid = blockIdx.x * 256 + threadIdx.x;   // 8192 threads
    if (gid < 2 * MPTS) {
        float x = ptgt[3 * gid + 0];
        float y = ptgt[3 * gid + 1];
        float z = ptgt[3 * gid + 2];
        float4 v;
        v.x = x; v.y = y; v.z = z;
        v.w = 0.5f * (x * x + y * y + z * z);
        ((float4*)ptgt4)[gid] = v;
    }
    for (int i = gid; i < NSTEPS * CTR_STRIDE; i += 8192) ctrs[i] = 0u;
}

__device__ __forceinline__ float frcp(float x) {
#if __has_builtin(__builtin_amdgcn_rcpf)
    return __builtin_amdgcn_rcpf(x);
#else
    return 1.f / x;
#endif
}
__device__ __forceinline__ float frsq(float x) {
#if __has_builtin(__builtin_amdgcn_rsqf)
    return __builtin_amdgcn_rsqf(x);
#else
    return 1.f / sqrtf(x);
#endif
}

#define DET3(a,b,c,d,e,f,g,h,i) \
    ((a)*((e)*(i)-(f)*(h)) - (b)*((d)*(i)-(f)*(g)) + (c)*((d)*(h)-(e)*(g)))

// Max-eigenpair of symmetric 4x4 via Newton on the characteristic quartic
// (monotone from Gershgorin upper bound) + cofactor-row eigenvector.
__device__ __forceinline__ void horn_quat(const float N[4][4], float q[4]) {
    float s = 1e-30f;
#pragma unroll
    for (int i = 0; i < 4; ++i)
#pragma unroll
        for (int j = 0; j < 4; ++j) s = fmaxf(s, fabsf(N[i][j]));
    float inv = frcp(s);
    float A[4][4], B[4][4];
#pragma unroll
    for (int i = 0; i < 4; ++i)
#pragma unroll
        for (int j = 0; j < 4; ++j) A[i][j] = N[i][j] * inv;
#pragma unroll
    for (int i = 0; i < 4; ++i)
#pragma unroll
        for (int j = i; j < 4; ++j) {
            float v = A[i][0]*A[0][j] + A[i][1]*A[1][j] + A[i][2]*A[2][j] + A[i][3]*A[3][j];
            B[i][j] = v; B[j][i] = v;
        }
    float p1 = A[0][0]+A[1][1]+A[2][2]+A[3][3];
    float p2 = B[0][0]+B[1][1]+B[2][2]+B[3][3];
    float p3 = 0.f, p4 = 0.f;
#pragma unroll
    for (int i = 0; i < 4; ++i)
#pragma unroll
        for (int j = 0; j < 4; ++j) { p3 += A[i][j]*B[i][j]; p4 += B[i][j]*B[i][j]; }
    float e1 = p1;
    float e2 = 0.5f*(e1*p1 - p2);
    float e3 = (e2*p1 - e1*p2 + p3)*(1.f/3.f);
    float e4 = 0.25f*(e3*p1 - e2*p2 + e1*p3 - p4);
    float lam = -3e38f;
#pragma unroll
    for (int i = 0; i < 4; ++i) {
        float r = A[i][i];
#pragma unroll
        for (int j = 0; j < 4; ++j) if (j != i) r += fabsf(A[i][j]);
        lam = fmaxf(lam, r);
    }
#pragma unroll
    for (int it = 0; it < 12; ++it) {
        float pv = (((lam - e1)*lam + e2)*lam - e3)*lam + e4;
        float dv = ((4.f*lam - 3.f*e1)*lam + 2.f*e2)*lam - e3;
        lam -= pv * frcp(dv);
    }
    float M[4][4];
#pragma unroll
    for (int i = 0; i < 4; ++i)
#pragma unroll
        for (int j = 0; j < 4; ++j) M[i][j] = A[i][j] - ((i == j) ? lam : 0.f);
    float C0 = DET3(M[1][1],M[1][2],M[1][3], M[2][1],M[2][2],M[2][3], M[3][1],M[3][2],M[3][3]);
    float C1 = DET3(M[0][0],M[0][2],M[0][3], M[2][0],M[2][2],M[2][3], M[3][0],M[3][2],M[3][3]);
    float C2 = DET3(M[0][0],M[0][1],M[0][3], M[1][0],M[1][1],M[1][3], M[3][0],M[3][1],M[3][3]);
    float C3 = DET3(M[0][0],M[0][1],M[0][2], M[1][0],M[1][1],M[1][2], M[2][0],M[2][1],M[2][2]);
    int is = 0; float cb = fabsf(C0);
    if (fabsf(C1) > cb) { cb = fabsf(C1); is = 1; }
    if (fabsf(C2) > cb) { cb = fabsf(C2); is = 2; }
    if (fabsf(C3) > cb) { cb = fabsf(C3); is = 3; }
    float v0, v1, v2, v3;
#define ROWCOF(a,b,c) { \
    v0 =  DET3(M[a][1],M[a][2],M[a][3], M[b][1],M[b][2],M[b][3], M[c][1],M[c][2],M[c][3]); \
    v1 = -DET3(M[a][0],M[a][2],M[a][3], M[b][0],M[b][2],M[b][3], M[c][0],M[c][2],M[c][3]); \
    v2 =  DET3(M[a][0],M[a][1],M[a][3], M[b][0],M[b][1],M[b][3], M[c][0],M[c][1],M[c][3]); \
    v3 = -DET3(M[a][0],M[a][1],M[a][2], M[b][0],M[b][1],M[b][2], M[c][0],M[c][1],M[c][2]); }
    if (is == 0)      ROWCOF(1,2,3)
    else if (is == 1) ROWCOF(0,2,3)
    else if (is == 2) ROWCOF(0,1,3)
    else              ROWCOF(0,1,2)
#undef ROWCOF
    float nr = frsq(v0*v0 + v1*v1 + v2*v2 + v3*v3);
    q[0] = v0*nr; q[1] = v1*nr; q[2] = v2*nr; q[3] = v3*nr;
}

#define FOR16(OP) OP(0) OP(1) OP(2) OP(3) OP(4) OP(5) OP(6) OP(7) \
                  OP(8) OP(9) OP(10) OP(11) OP(12) OP(13) OP(14) OP(15)

// 512 blocks x 512 threads (2 blocks/CU, 4 waves/SIMD — double R12's TLP to
// hide the latency-bound NN scan; per-wave regs unchanged vs R12 so no spill,
// unlike R9's 4-blocks/CU 64-VGPR squeeze). Block = 16 source points of batch
// b = bid>>8; wave w (0..7) scans target slice [w*512,(w+1)*512) = 8 k-iters.
// Per step: NN -> per-block private atomic stores -> arrival RMW chain ->
// MASTER (block 0) gathers 512x16, Horn Newton-quartic solve, publishes R,t +
// striped flags (1=continue,2=done); workers poll flag, read R,t.
// Fence-free agent-atomic pattern proven R5-R12.
__global__ __launch_bounds__(512, 4) void icp_main(
    const float* __restrict__ psrc, float* __restrict__ ws,
    float* __restrict__ out) {

    float* ptgt4 = ws;
    float* acc = ws + ACC_OFF;
    unsigned* ctrs = (unsigned*)(ws + CTR_OFF);
    float* stpub = ws + STPUB_OFF;

    __shared__ float st[2][13];     // per batch: Rcum(9), tcum(3), err(1)
    __shared__ unsigned keys[8][16];
    __shared__ float red[16][16];
    __shared__ float gred[32][16];  // master gather partials [group][comp]
    __shared__ float asum[2][16];
    __shared__ int contflag;        // 1=continue, 2=done

    const int tid = threadIdx.x;
    const int bid = blockIdx.x;
    const int b = bid >> 8;             // batch (256 blocks each)
    const int n0 = (bid & 255) * 16;    // this block's 16 source points

    if (tid < 2) {
        st[tid][0] = 1.f; st[tid][1] = 0.f; st[tid][2] = 0.f;
        st[tid][3] = 0.f; st[tid][4] = 1.f; st[tid][5] = 0.f;
        st[tid][6] = 0.f; st[tid][7] = 0.f; st[tid][8] = 1.f;
        st[tid][9] = 0.f; st[tid][10] = 0.f; st[tid][11] = 0.f;
        st[tid][12] = 0.f;
    }
    __syncthreads();

    const int w = tid >> 6, lane = tid & 63;   // w in 0..7
    const int m0 = w * 512 + lane;
    const float4* tpb = (const float4*)ptgt4 + ((size_t)b * MPTS + m0);
    const float* ps = psrc + ((size_t)b * NPTS + n0) * 3;

    for (int step = 0; step < NSTEPS; ++step) {
        float R00 = st[b][0], R01 = st[b][1], R02 = st[b][2];
        float R10 = st[b][3], R11 = st[b][4], R12 = st[b][5];
        float R20 = st[b][6], R21 = st[b][7], R22 = st[b][8];
        float t0 = st[b][9], t1 = st[b][10], t2 = st[b][11];

#define DECLP(i) float px##i, py##i, pz##i;
        FOR16(DECLP)
#undef DECLP
#define LOADP(i) { float x = ps[3*(i)], y = ps[3*(i)+1], z = ps[3*(i)+2]; \
        px##i = fmaf(R00, x, fmaf(R01, y, fmaf(R02, z, t0))); \
        py##i = fmaf(R10, x, fmaf(R11, y, fmaf(R12, z, t1))); \
        pz##i = fmaf(R20, x, fmaf(R21, y, fmaf(R22, z, t2))); }
        FOR16(LOADP)
#undef LOADP

        // s = p.t - |t|^2/2; argmax s == argmin dist (strict > keeps first max)
#define DECLB(i) float bs##i = -3.0e38f; int ix##i = m0;
        FOR16(DECLB)
#undef DECLB

        float4 tc0 = tpb[0];
        float4 tc1 = tpb[64];
        int mreg = m0;
#pragma unroll
        for (int k = 0; k < 8; ++k) {
            float4 tnx = tpb[((k + 2) & 7) * 64];  // wraps harmlessly
            float tx = tc0.x, ty = tc0.y, tz = tc0.z, htn = tc0.w;
#define PAIR(i) { float s = fmaf(px##i, tx, fmaf(py##i, ty, fmaf(pz##i, tz, -htn))); \
            if (s > bs##i) { bs##i = s; ix##i = mreg; } }
            FOR16(PAIR)
#undef PAIR
            mreg += 64;
            tc0 = tc1;
            tc1 = tnx;
        }

        // wave argmax via order-preserving packed key: score hi-20 | (4095-m)
#define REDKEY(i) { unsigned ub = __float_as_uint(bs##i); \
        unsigned u = ((int)ub >= 0) ? (ub | 0x80000000u) : ~ub; \
        unsigned key = (u & 0xFFFFF000u) | (4095u - (unsigned)ix##i); \
        for (int off = 32; off; off >>= 1) { \
            unsigned o = (unsigned)__shfl_xor((int)key, off); \
            key = key > o ? key : o; } \
        if (lane == 0) keys[w][i] = key; }
        FOR16(REDKEY)
#undef REDKEY
        __syncthreads();

        if (tid < 16) {
            unsigned key = keys[0][tid];
#pragma unroll
            for (int ww = 1; ww < 8; ++ww) {
                unsigned o = keys[ww][tid];
                key = key > o ? key : o;
            }
            int m = 4095 - (int)(key & 0xFFFu);
            float4 qq = ((const float4*)ptgt4)[(size_t)b * MPTS + m];
            const float* pp = psrc + ((size_t)b * NPTS + n0 + tid) * 3;
            float x = pp[0], y = pp[1], z = pp[2];
            float px = fmaf(R00, x, fmaf(R01, y, fmaf(R02, z, t0)));
            float py = fmaf(R10, x, fmaf(R11, y, fmaf(R12, z, t1)));
            float pz = fmaf(R20, x, fmaf(R21, y, fmaf(R22, z, t2)));
            float dx = px - qq.x, dy = py - qq.y, dz = pz - qq.z;
            float dist = sqrtf(dx * dx + dy * dy + dz * dz);
            red[tid][0] = px; red[tid][1] = py; red[tid][2] = pz;
            red[tid][3] = qq.x; red[tid][4] = qq.y; red[tid][5] = qq.z;
            red[tid][6] = px * qq.x;  red[tid][7] = px * qq.y;  red[tid][8] = px * qq.z;
            red[tid][9] = py * qq.x;  red[tid][10] = py * qq.y; red[tid][11] = py * qq.z;
            red[tid][12] = pz * qq.x; red[tid][13] = pz * qq.y; red[tid][14] = pz * qq.z;
            red[tid][15] = dist;
        }
        __syncthreads();
        if (tid < 16) {
            float s = 0.f;
#pragma unroll
            for (int r = 0; r < 16; ++r) s += red[r][tid];
            __hip_atomic_store(&acc[((size_t)step * NBLK + bid) * 16 + tid], s,
                               __ATOMIC_RELAXED, __HIP_MEMORY_SCOPE_AGENT);
        }

        // ---- arrival (all blocks), then master/worker split ----
        unsigned* stepc = ctrs + step * CTR_STRIDE;
        __syncthreads();   // drains the acc stores before arrival RMW
        if (tid == 0) {
            unsigned* sub = stepc + (bid & (NSUB - 1)) * 16;
            unsigned old = __hip_atomic_fetch_add(sub, 1u, __ATOMIC_RELAXED,
                                                  __HIP_MEMORY_SCOPE_AGENT);
            if (old == (unsigned)(NBLK / NSUB) - 1u)
                __hip_atomic_fetch_add(stepc + 512, 1u, __ATOMIC_RELAXED,
                                       __HIP_MEMORY_SCOPE_AGENT);
        }

        if (bid == 0) {
            if (tid == 0) {
                while (__hip_atomic_load(stepc + 512, __ATOMIC_RELAXED,
                                         __HIP_MEMORY_SCOPE_AGENT) < (unsigned)NSUB) {
                    __builtin_amdgcn_s_sleep(1);
                }
            }
            __syncthreads();
            // gather 512 slots x 16 comps with plain loads (region first
            // touched post-barrier; atomic stores bypassed L2 -> L3 correct)
            {
                const float* accs = acc + (size_t)step * NBLK * 16;
                int c = tid & 15, g = tid >> 4;       // 32 groups x 16 slots
                float ssum = 0.f;
#pragma unroll
                for (int i = 0; i < 16; ++i)
                    ssum += accs[(size_t)(g * 16 + i) * 16 + c];
                gred[g][c] = ssum;
            }
            __syncthreads();
            if (tid < 32) {
                int bb = tid >> 4, c = tid & 15;
                float s = 0.f;
#pragma unroll
                for (int g = 0; g < 16; ++g) s += gred[bb * 16 + g][c];
                asum[bb][c] = s;
            }
            __syncthreads();
            if (tid == 0) {
                float err0 = asum[0][15] * (1.f / NPTS);
                float err1 = asum[1][15] * (1.f / NPTS);
                bool conv = (fabsf(err0 - st[0][12]) < ICP_TOL) &&
                            (fabsf(err1 - st[1][12]) < ICP_TOL);
                contflag = conv ? 2 : 1;
            }
            __syncthreads();
            if (contflag == 1 && tid < 2) {
                float a[16];
                for (int i = 0; i < 16; ++i) a[i] = asum[tid][i];
                const float inv_n = 1.f / NPTS;
                float pmx = a[0]*inv_n, pmy = a[1]*inv_n, pmz = a[2]*inv_n;
                float qmx = a[3]*inv_n, qmy = a[4]*inv_n, qmz = a[5]*inv_n;
                float H[3][3];
                for (int i = 0; i < 3; ++i)
                    for (int j = 0; j < 3; ++j)
                        H[i][j] = a[6 + 3*i + j] - a[i]*a[3 + j]*inv_n;
                float Sxx=H[0][0], Sxy=H[0][1], Sxz=H[0][2];
                float Syx=H[1][0], Syy=H[1][1], Syz=H[1][2];
                float Szx=H[2][0], Szy=H[2][1], Szz=H[2][2];
                float Nm[4][4];
                Nm[0][0] = Sxx+Syy+Szz; Nm[0][1] = Syz-Szy;
                Nm[0][2] = Szx-Sxz;     Nm[0][3] = Sxy-Syx;
                Nm[1][1] = Sxx-Syy-Szz; Nm[1][2] = Sxy+Syx; Nm[1][3] = Szx+Sxz;
                Nm[2][2] = -Sxx+Syy-Szz; Nm[2][3] = Syz+Szy;
                Nm[3][3] = -Sxx-Syy+Szz;
                Nm[1][0]=Nm[0][1]; Nm[2][0]=Nm[0][2]; Nm[3][0]=Nm[0][3];
                Nm[2][1]=Nm[1][2]; Nm[3][1]=Nm[1][3]; Nm[3][2]=Nm[2][3];
                float qv[4];
                horn_quat(Nm, qv);
                float qw = qv[0], qx = qv[1], qy = qv[2], qz = qv[3];
                float R00n = 1.f - 2.f*(qy*qy + qz*qz);
                float R01n = 2.f*(qx*qy - qw*qz);
                float R02n = 2.f*(qx*qz + qw*qy);
                float R10n = 2.f*(qx*qy + qw*qz);
                float R11n = 1.f - 2.f*(qx*qx + qz*qz);
                float R12n = 2.f*(qy*qz - qw*qx);
                float R20n = 2.f*(qx*qz - qw*qy);
                float R21n = 2.f*(qy*qz + qw*qx);
                float R22n = 1.f - 2.f*(qx*qx + qy*qy);
                float tx = qmx - (R00n*pmx + R01n*pmy + R02n*pmz);
                float ty = qmy - (R10n*pmx + R11n*pmy + R12n*pmz);
                float tz = qmz - (R20n*pmx + R21n*pmy + R22n*pmz);
                float C00=st[tid][0], C01=st[tid][1], C02=st[tid][2];
                float C10=st[tid][3], C11=st[tid][4], C12=st[tid][5];
                float C20=st[tid][6], C21=st[tid][7], C22=st[tid][8];
                float T0=st[tid][9], T1=st[tid][10], T2=st[tid][11];
                float ns[12];
                ns[0] = R00n*C00 + R01n*C10 + R02n*C20;
                ns[1] = R00n*C01 + R01n*C11 + R02n*C21;
                ns[2] = R00n*C02 + R01n*C12 + R02n*C22;
                ns[3] = R10n*C00 + R11n*C10 + R12n*C20;
                ns[4] = R10n*C01 + R11n*C11 + R12n*C21;
                ns[5] = R10n*C02 + R11n*C12 + R12n*C22;
                ns[6] = R20n*C00 + R21n*C10 + R22n*C20;
                ns[7] = R20n*C01 + R21n*C11 + R22n*C21;
                ns[8] = R20n*C02 + R21n*C12 + R22n*C22;
                ns[9]  = R00n*T0 + R01n*T1 + R02n*T2 + tx;
                ns[10] = R10n*T0 + R11n*T1 + R12n*T2 + ty;
                ns[11] = R20n*T0 + R21n*T1 + R22n*T2 + tz;
                for (int i = 0; i < 12; ++i) {
                    st[tid][i] = ns[i];
                    __hip_atomic_store(&stpub[step*32 + tid*16 + i], ns[i],
                                       __ATOMIC_RELAXED, __HIP_MEMORY_SCOPE_AGENT);
                }
                st[tid][12] = asum[tid][15] * (1.f / NPTS);
            }
            __syncthreads();   // drains stpub stores before flag release
            if (tid == 0) {
                unsigned fv = (unsigned)contflag;
#pragma unroll
                for (int f = 0; f < 32; ++f)
                    __hip_atomic_store(stepc + 1024 + f*16, fv,
                                       __ATOMIC_RELAXED, __HIP_MEMORY_SCOPE_AGENT);
            }
            __syncthreads();
        } else {
            if (tid == 0) {
                unsigned* myflag = stepc + 1024 + (bid & 31) * 16;
                unsigned fv;
                while ((fv = __hip_atomic_load(myflag, __ATOMIC_RELAXED,
                                               __HIP_MEMORY_SCOPE_AGENT)) == 0u) {
                    __builtin_amdgcn_s_sleep(2);
                }
                contflag = (int)fv;
                if (fv == 1u) {
                    for (int i = 0; i < 12; ++i)
                        st[b][i] = __hip_atomic_load(&stpub[step*32 + b*16 + i],
                                                     __ATOMIC_RELAXED,
                                                     __HIP_MEMORY_SCOPE_AGENT);
                }
            }
            __syncthreads();
        }
        if (contflag == 2) break;   // uniform across the grid
    }

    if (bid == 0 && tid < 2) {
        float r00 = st[tid][0], r01 = st[tid][1], r02 = st[tid][2];
        float r10 = st[tid][3], r11 = st[tid][4], r12 = st[tid][5];
        float r20 = st[tid][6], r21 = st[tid][7], r22 = st[tid][8];
        float qw = 0.5f * sqrtf(fmaxf(1.f + r00 + r11 + r22, 1e-12f));
        float qx = 0.5f * sqrtf(fmaxf(1.f + r00 - r11 - r22, 1e-12f));
        float qy = 0.5f * sqrtf(fmaxf(1.f - r00 + r11 - r22, 1e-12f));
        float qz = 0.5f * sqrtf(fmaxf(1.f - r00 - r11 + r22, 1e-12f));
        qx = (r21 - r12 >= 0.f) ? qx : -qx;
        qy = (r02 - r20 >= 0.f) ? qy : -qy;
        qz = (r10 - r01 >= 0.f) ? qz : -qz;
        out[tid * 7 + 0] = st[tid][9];
        out[tid * 7 + 1] = st[tid][10];
        out[tid * 7 + 2] = st[tid][11];
        out[tid * 7 + 3] = qx;
        out[tid * 7 + 4] = qy;
        out[tid * 7 + 5] = qz;
        out[tid * 7 + 6] = qw;
    }
}

extern "C" void kernel_launch(void* const* d_in, const int* in_sizes, int n_in,
                              void* d_out, int out_size, void* d_ws, size_t ws_size,
                              hipStream_t stream) {
    const float* psrc = (const float*)d_in[0];
    const float* ptgt = (const float*)d_in[1];
    float* out = (float*)d_out;
    float* ws = (float*)d_ws;

    init_kernel<<<32, 256, 0, stream>>>(ptgt, ws);
    icp_main<<<NBLK, 512, 0, stream>>>(psrc, ws, out);
}

// Round 16
// 194.590 us; speedup vs baseline: 1.0633x; 1.0633x over previous
//
#include <hip/hip_runtime.h>
#include <math.h>

#define NPTS 4096
#define MPTS 4096
#define NSTEPS 8
#define ICP_TOL 1e-6f
#define NBLK 256    // 1 block/CU: residency guaranteed at ANY LDS/VGPR -> barrier can't deadlock
#define NSUB 16     // arrival sub-counters, 16 blocks each

// ws layout (floats):
//   ptgt4 : [0, 32768)         interleaved {x,y,z,0.5*|t|^2}, 2*4096 targets
//   acc   : [32768, 65536)     [step][block(256)][16] per-block partials (atomic stores)
//   ctrs  : words at 98304, 1536/step: subs at c*16 (c<16), master at 512,
//           flags at 1024+f*16 (f<16); value 0=wait, 1=continue, 2=done
//   stpub : floats at 110592, 32/step: [step][batch][16] published R(9)+t(3)
#define ACC_OFF 32768
#define CTR_OFF 98304
#define CTR_STRIDE 1536
#define STPUB_OFF 110592

__global__ void init_kernel(const float* __restrict__ ptgt, float* __restrict__ ws) {
    float* ptgt4 = ws;
    unsigned* ctrs = (unsigned*)(ws + CTR_OFF);
    int gid = blockIdx.x * 256 + threadIdx.x;   // 8192 threads
    if (gid < 2 * MPTS) {
        float x = ptgt[3 * gid + 0];
        float y = ptgt[3 * gid + 1];
        float z = ptgt[3 * gid + 2];
        float4 v;
        v.x = x; v.y = y; v.z = z;
        v.w = 0.5f * (x * x + y * y + z * z);
        ((float4*)ptgt4)[gid] = v;
    }
    for (int i = gid; i < NSTEPS * CTR_STRIDE; i += 8192) ctrs[i] = 0u;
}

__device__ __forceinline__ float frcp(float x) {
#if __has_builtin(__builtin_amdgcn_rcpf)
    return __builtin_amdgcn_rcpf(x);
#else
    return 1.f / x;
#endif
}
__device__ __forceinline__ float frsq(float x) {
#if __has_builtin(__builtin_amdgcn_rsqf)
    return __builtin_amdgcn_rsqf(x);
#else
    return 1.f / sqrtf(x);
#endif
}

#define DET3(a,b,c,d,e,f,g,h,i) \
    ((a)*((e)*(i)-(f)*(h)) - (b)*((d)*(i)-(f)*(g)) + (c)*((d)*(h)-(e)*(g)))

// Max-eigenpair of symmetric 4x4: Newton on characteristic quartic from a
// Gershgorin upper bound + cofactor-row eigenvector. ~1200-cyc serial chain.
__device__ __forceinline__ void horn_quat(const float N[4][4], float q[4]) {
    float s = 1e-30f;
#pragma unroll
    for (int i = 0; i < 4; ++i)
#pragma unroll
        for (int j = 0; j < 4; ++j) s = fmaxf(s, fabsf(N[i][j]));
    float inv = frcp(s);
    float A[4][4], B[4][4];
#pragma unroll
    for (int i = 0; i < 4; ++i)
#pragma unroll
        for (int j = 0; j < 4; ++j) A[i][j] = N[i][j] * inv;
#pragma unroll
    for (int i = 0; i < 4; ++i)
#pragma unroll
        for (int j = i; j < 4; ++j) {
            float v = A[i][0]*A[0][j] + A[i][1]*A[1][j] + A[i][2]*A[2][j] + A[i][3]*A[3][j];
            B[i][j] = v; B[j][i] = v;
        }
    float p1 = A[0][0]+A[1][1]+A[2][2]+A[3][3];
    float p2 = B[0][0]+B[1][1]+B[2][2]+B[3][3];
    float p3 = 0.f, p4 = 0.f;
#pragma unroll
    for (int i = 0; i < 4; ++i)
#pragma unroll
        for (int j = 0; j < 4; ++j) { p3 += A[i][j]*B[i][j]; p4 += B[i][j]*B[i][j]; }
    float e1 = p1;
    float e2 = 0.5f*(e1*p1 - p2);
    float e3 = (e2*p1 - e1*p2 + p3)*(1.f/3.f);
    float e4 = 0.25f*(e3*p1 - e2*p2 + e1*p3 - p4);
    float lam = -3e38f;
#pragma unroll
    for (int i = 0; i < 4; ++i) {
        float r = A[i][i];
#pragma unroll
        for (int j = 0; j < 4; ++j) if (j != i) r += fabsf(A[i][j]);
        lam = fmaxf(lam, r);
    }
#pragma unroll
    for (int it = 0; it < 12; ++it) {
        float pv = (((lam - e1)*lam + e2)*lam - e3)*lam + e4;
        float dv = ((4.f*lam - 3.f*e1)*lam + 2.f*e2)*lam - e3;
        lam -= pv * frcp(dv);
    }
    float M[4][4];
#pragma unroll
    for (int i = 0; i < 4; ++i)
#pragma unroll
        for (int j = 0; j < 4; ++j) M[i][j] = A[i][j] - ((i == j) ? lam : 0.f);
    float C0 = DET3(M[1][1],M[1][2],M[1][3], M[2][1],M[2][2],M[2][3], M[3][1],M[3][2],M[3][3]);
    float C1 = DET3(M[0][0],M[0][2],M[0][3], M[2][0],M[2][2],M[2][3], M[3][0],M[3][2],M[3][3]);
    float C2 = DET3(M[0][0],M[0][1],M[0][3], M[1][0],M[1][1],M[1][3], M[3][0],M[3][1],M[3][3]);
    float C3 = DET3(M[0][0],M[0][1],M[0][2], M[1][0],M[1][1],M[1][2], M[2][0],M[2][1],M[2][2]);
    int is = 0; float cb = fabsf(C0);
    if (fabsf(C1) > cb) { cb = fabsf(C1); is = 1; }
    if (fabsf(C2) > cb) { cb = fabsf(C2); is = 2; }
    if (fabsf(C3) > cb) { cb = fabsf(C3); is = 3; }
    float v0, v1, v2, v3;
#define ROWCOF(a,b,c) { \
    v0 =  DET3(M[a][1],M[a][2],M[a][3], M[b][1],M[b][2],M[b][3], M[c][1],M[c][2],M[c][3]); \
    v1 = -DET3(M[a][0],M[a][2],M[a][3], M[b][0],M[b][2],M[b][3], M[c][0],M[c][2],M[c][3]); \
    v2 =  DET3(M[a][0],M[a][1],M[a][3], M[b][0],M[b][1],M[b][3], M[c][0],M[c][1],M[c][3]); \
    v3 = -DET3(M[a][0],M[a][1],M[a][2], M[b][0],M[b][1],M[b][2], M[c][0],M[c][1],M[c][2]); }
    if (is == 0)      ROWCOF(1,2,3)
    else if (is == 1) ROWCOF(0,2,3)
    else if (is == 2) ROWCOF(0,1,3)
    else              ROWCOF(0,1,2)
#undef ROWCOF
    float nr = frsq(v0*v0 + v1*v1 + v2*v2 + v3*v3);
    q[0] = v0*nr; q[1] = v1*nr; q[2] = v2*nr; q[3] = v3*nr;
}

#define FOR16(OP) OP(0) OP(1) OP(2) OP(3) OP(4) OP(5) OP(6) OP(7) \
                  OP(8) OP(9) OP(10) OP(11) OP(12) OP(13) OP(14) OP(15)

// 256 blocks x 512 threads, persistent, 1 block/CU (residency guaranteed ->
// the all-arrive barrier cannot deadlock; this is what killed R14/R15 at
// 2 blocks/CU with 50 KB LDS). Targets staged in LDS once per kernel.
// Block = 32 source points of batch b = bid>>7, as two 16-point passes; wave
// w (0..7) scans target slice [w*512,(w+1)*512) per pass -> 16 k-iters/wave/
// step, identical per-wave work and VGPR footprint to R12 (2 waves/SIMD TLP).
// Handshake: master-block Kabsch, fence-free agent atomics (proven R5-R13).
__global__ __launch_bounds__(512, 2) void icp_main(
    const float* __restrict__ psrc, float* __restrict__ ws,
    float* __restrict__ out) {

    float* ptgt4 = ws;
    float* acc = ws + ACC_OFF;
    unsigned* ctrs = (unsigned*)(ws + CTR_OFF);
    float* stpub = ws + STPUB_OFF;

    __shared__ float tshx[MPTS];    // 16 KB
    __shared__ float tshy[MPTS];    // 16 KB
    __shared__ float tshz[MPTS];    // 16 KB
    __shared__ float st[2][13];
    __shared__ unsigned keys[8][16];
    __shared__ float red[16][16];
    __shared__ float gred[2][16][16];
    __shared__ float asum[2][16];
    __shared__ int contflag;

    const int tid = threadIdx.x;
    const int bid = blockIdx.x;
    const int b = bid >> 7;             // batch (128 blocks each)
    const int n0 = (bid & 127) * 32;    // this block's 32 source points

    // ---- one-time target staging (amortized over all 8 steps) ----
    {
        const float4* tp4 = (const float4*)ptgt4 + (size_t)b * MPTS;
        for (int i = tid; i < MPTS; i += 512) {
            float4 v = tp4[i];
            tshx[i] = v.x; tshy[i] = v.y; tshz[i] = v.z;
        }
    }
    if (tid < 2) {
        st[tid][0] = 1.f; st[tid][1] = 0.f; st[tid][2] = 0.f;
        st[tid][3] = 0.f; st[tid][4] = 1.f; st[tid][5] = 0.f;
        st[tid][6] = 0.f; st[tid][7] = 0.f; st[tid][8] = 1.f;
        st[tid][9] = 0.f; st[tid][10] = 0.f; st[tid][11] = 0.f;
        st[tid][12] = 0.f;
    }
    __syncthreads();

    const int w = tid >> 6, lane = tid & 63;   // w in 0..7
    const int m0 = w * 512 + lane;

    for (int step = 0; step < NSTEPS; ++step) {
        float R00 = st[b][0], R01 = st[b][1], R02 = st[b][2];
        float R10 = st[b][3], R11 = st[b][4], R12 = st[b][5];
        float R20 = st[b][6], R21 = st[b][7], R22 = st[b][8];
        float t0 = st[b][9], t1 = st[b][10], t2 = st[b][11];

        float sacc = 0.f;   // per-component accumulator (tid<16)

        for (int p = 0; p < 2; ++p) {
            const int np = n0 + p * 16;
            const float* ps = psrc + ((size_t)b * NPTS + np) * 3;

#define DECLP(i) float px##i, py##i, pz##i;
            FOR16(DECLP)
#undef DECLP
#define LOADP(i) { float x = ps[3*(i)], y = ps[3*(i)+1], z = ps[3*(i)+2]; \
            px##i = fmaf(R00, x, fmaf(R01, y, fmaf(R02, z, t0))); \
            py##i = fmaf(R10, x, fmaf(R11, y, fmaf(R12, z, t1))); \
            pz##i = fmaf(R20, x, fmaf(R21, y, fmaf(R22, z, t2))); }
            FOR16(LOADP)
#undef LOADP

            // s = p.t - |t|^2/2; argmax s == argmin dist
#define DECLB(i) float bs##i = -3.0e38f; int ix##i = m0;
            FOR16(DECLB)
#undef DECLB

            float tcx = tshx[m0], tcy = tshy[m0], tcz = tshz[m0];
            int mreg = m0;
#pragma unroll
            for (int k = 0; k < 8; ++k) {
                int mn = m0 + ((k + 1) & 7) * 64;   // next-iter prefetch (wraps)
                float tnx = tshx[mn], tny = tshy[mn], tnz = tshz[mn];
                float htn = 0.5f * (tcx * tcx + tcy * tcy + tcz * tcz);
                float tx = tcx, ty = tcy, tz = tcz;
#define PAIR(i) { float s = fmaf(px##i, tx, fmaf(py##i, ty, fmaf(pz##i, tz, -htn))); \
                if (s > bs##i) { bs##i = s; ix##i = mreg; } }
                FOR16(PAIR)
#undef PAIR
                mreg += 64;
                tcx = tnx; tcy = tny; tcz = tnz;
            }

            // wave argmax via order-preserving packed key: score hi-20 | (4095-m)
#define REDKEY(i) { unsigned ub = __float_as_uint(bs##i); \
            unsigned u = ((int)ub >= 0) ? (ub | 0x80000000u) : ~ub; \
            unsigned key = (u & 0xFFFFF000u) | (4095u - (unsigned)ix##i); \
            for (int off = 32; off; off >>= 1) { \
                unsigned o = (unsigned)__shfl_xor((int)key, off); \
                key = key > o ? key : o; } \
            if (lane == 0) keys[w][i] = key; }
            FOR16(REDKEY)
#undef REDKEY
            __syncthreads();

            if (tid < 16) {
                unsigned key = keys[0][tid];
#pragma unroll
                for (int ww = 1; ww < 8; ++ww) {
                    unsigned o = keys[ww][tid];
                    key = key > o ? key : o;
                }
                int m = 4095 - (int)(key & 0xFFFu);
                float qx2 = tshx[m], qy2 = tshy[m], qz2 = tshz[m];
                const float* pp = psrc + ((size_t)b * NPTS + np + tid) * 3;
                float x = pp[0], y = pp[1], z = pp[2];
                float px = fmaf(R00, x, fmaf(R01, y, fmaf(R02, z, t0)));
                float py = fmaf(R10, x, fmaf(R11, y, fmaf(R12, z, t1)));
                float pz = fmaf(R20, x, fmaf(R21, y, fmaf(R22, z, t2)));
                float dx = px - qx2, dy = py - qy2, dz = pz - qz2;
                float dist = sqrtf(dx * dx + dy * dy + dz * dz);
                red[tid][0] = px; red[tid][1] = py; red[tid][2] = pz;
                red[tid][3] = qx2; red[tid][4] = qy2; red[tid][5] = qz2;
                red[tid][6] = px * qx2;  red[tid][7] = px * qy2;  red[tid][8] = px * qz2;
                red[tid][9] = py * qx2;  red[tid][10] = py * qy2; red[tid][11] = py * qz2;
                red[tid][12] = pz * qx2; red[tid][13] = pz * qy2; red[tid][14] = pz * qz2;
                red[tid][15] = dist;
            }
            __syncthreads();
            if (tid < 16) {
                float s = 0.f;
#pragma unroll
                for (int r = 0; r < 16; ++r) s += red[r][tid];
                sacc += s;
            }
            __syncthreads();   // keys/red reused next pass
        }

        if (tid < 16) {
            __hip_atomic_store(&acc[((size_t)step * NBLK + bid) * 16 + tid], sacc,
                               __ATOMIC_RELAXED, __HIP_MEMORY_SCOPE_AGENT);
        }

        // ---- arrival (all blocks), then master/worker split ----
        unsigned* stepc = ctrs + step * CTR_STRIDE;
        __syncthreads();   // drains the acc stores before arrival RMW
        if (tid == 0) {
            unsigned* sub = stepc + (bid & (NSUB - 1)) * 16;
            unsigned old = __hip_atomic_fetch_add(sub, 1u, __ATOMIC_RELAXED,
                                                  __HIP_MEMORY_SCOPE_AGENT);
            if (old == (unsigned)(NBLK / NSUB) - 1u)
                __hip_atomic_fetch_add(stepc + 512, 1u, __ATOMIC_RELAXED,
                                       __HIP_MEMORY_SCOPE_AGENT);
        }

        if (bid == 0) {
            if (tid == 0) {
                while (__hip_atomic_load(stepc + 512, __ATOMIC_RELAXED,
                                         __HIP_MEMORY_SCOPE_AGENT) < (unsigned)NSUB) {
                    __builtin_amdgcn_s_sleep(1);
                }
            }
            __syncthreads();
            // gather 256 slots x 16 comps (plain loads; region first touched
            // post-barrier; atomic stores bypassed L2 -> L3 serves correct)
            {
                const float* accs = acc + (size_t)step * NBLK * 16;
                int bb = tid >> 8;              // 0..1
                int rem = tid & 255;
                int c = rem & 15, g = rem >> 4; // 16 groups x 8 slots per batch
                float ssum = 0.f;
#pragma unroll
                for (int i = 0; i < 8; ++i)
                    ssum += accs[(size_t)(bb * 128 + g * 8 + i) * 16 + c];
                gred[bb][g][c] = ssum;
            }
            __syncthreads();
            if (tid < 32) {
                int bb = tid >> 4, c = tid & 15;
                float s = 0.f;
#pragma unroll
                for (int g = 0; g < 16; ++g) s += gred[bb][g][c];
                asum[bb][c] = s;
            }
            __syncthreads();
            if (tid == 0) {
                float err0 = asum[0][15] * (1.f / NPTS);
                float err1 = asum[1][15] * (1.f / NPTS);
                bool conv = (fabsf(err0 - st[0][12]) < ICP_TOL) &&
                            (fabsf(err1 - st[1][12]) < ICP_TOL);
                contflag = conv ? 2 : 1;
            }
            __syncthreads();
            if (contflag == 1 && tid < 2) {
                float a[16];
                for (int i = 0; i < 16; ++i) a[i] = asum[tid][i];
                const float inv_n = 1.f / NPTS;
                float pmx = a[0]*inv_n, pmy = a[1]*inv_n, pmz = a[2]*inv_n;
                float qmx = a[3]*inv_n, qmy = a[4]*inv_n, qmz = a[5]*inv_n;
                float H[3][3];
                for (int i = 0; i < 3; ++i)
                    for (int j = 0; j < 3; ++j)
                        H[i][j] = a[6 + 3*i + j] - a[i]*a[3 + j]*inv_n;
                float Sxx=H[0][0], Sxy=H[0][1], Sxz=H[0][2];
                float Syx=H[1][0], Syy=H[1][1], Syz=H[1][2];
                float Szx=H[2][0], Szy=H[2][1], Szz=H[2][2];
                float Nm[4][4];
                Nm[0][0] = Sxx+Syy+Szz; Nm[0][1] = Syz-Szy;
                Nm[0][2] = Szx-Sxz;     Nm[0][3] = Sxy-Syx;
                Nm[1][1] = Sxx-Syy-Szz; Nm[1][2] = Sxy+Syx; Nm[1][3] = Szx+Sxz;
                Nm[2][2] = -Sxx+Syy-Szz; Nm[2][3] = Syz+Szy;
                Nm[3][3] = -Sxx-Syy+Szz;
                Nm[1][0]=Nm[0][1]; Nm[2][0]=Nm[0][2]; Nm[3][0]=Nm[0][3];
                Nm[2][1]=Nm[1][2]; Nm[3][1]=Nm[1][3]; Nm[3][2]=Nm[2][3];
                float qv[4];
                horn_quat(Nm, qv);
                float qw = qv[0], qx = qv[1], qy = qv[2], qz = qv[3];
                float R00n = 1.f - 2.f*(qy*qy + qz*qz);
                float R01n = 2.f*(qx*qy - qw*qz);
                float R02n = 2.f*(qx*qz + qw*qy);
                float R10n = 2.f*(qx*qy + qw*qz);
                float R11n = 1.f - 2.f*(qx*qx + qz*qz);
                float R12n = 2.f*(qy*qz - qw*qx);
                float R20n = 2.f*(qx*qz - qw*qy);
                float R21n = 2.f*(qy*qz + qw*qx);
                float R22n = 1.f - 2.f*(qx*qx + qy*qy);
                float tx = qmx - (R00n*pmx + R01n*pmy + R02n*pmz);
                float ty = qmy - (R10n*pmx + R11n*pmy + R12n*pmz);
                float tz = qmz - (R20n*pmx + R21n*pmy + R22n*pmz);
                float C00=st[tid][0], C01=st[tid][1], C02=st[tid][2];
                float C10=st[tid][3], C11=st[tid][4], C12=st[tid][5];
                float C20=st[tid][6], C21=st[tid][7], C22=st[tid][8];
                float T0=st[tid][9], T1=st[tid][10], T2=st[tid][11];
                float ns[12];
                ns[0] = R00n*C00 + R01n*C10 + R02n*C20;
                ns[1] = R00n*C01 + R01n*C11 + R02n*C21;
                ns[2] = R00n*C02 + R01n*C12 + R02n*C22;
                ns[3] = R10n*C00 + R11n*C10 + R12n*C20;
                ns[4] = R10n*C01 + R11n*C11 + R12n*C21;
                ns[5] = R10n*C02 + R11n*C12 + R12n*C22;
                ns[6] = R20n*C00 + R21n*C10 + R22n*C20;
                ns[7] = R20n*C01 + R21n*C11 + R22n*C21;
                ns[8] = R20n*C02 + R21n*C12 + R22n*C22;
                ns[9]  = R00n*T0 + R01n*T1 + R02n*T2 + tx;
                ns[10] = R10n*T0 + R11n*T1 + R12n*T2 + ty;
                ns[11] = R20n*T0 + R21n*T1 + R22n*T2 + tz;
                for (int i = 0; i < 12; ++i) {
                    st[tid][i] = ns[i];
                    __hip_atomic_store(&stpub[step*32 + tid*16 + i], ns[i],
                                       __ATOMIC_RELAXED, __HIP_MEMORY_SCOPE_AGENT);
                }
                st[tid][12] = asum[tid][15] * (1.f / NPTS);
            }
            __syncthreads();   // drains stpub stores before flag release
            if (tid == 0) {
                unsigned fv = (unsigned)contflag;
#pragma unroll
                for (int f = 0; f < NSUB; ++f)
                    __hip_atomic_store(stepc + 1024 + f*16, fv,
                                       __ATOMIC_RELAXED, __HIP_MEMORY_SCOPE_AGENT);
            }
            __syncthreads();
        } else {
            if (tid == 0) {
                unsigned* myflag = stepc + 1024 + (bid & (NSUB - 1)) * 16;
                unsigned fv;
                while ((fv = __hip_atomic_load(myflag, __ATOMIC_RELAXED,
                                               __HIP_MEMORY_SCOPE_AGENT)) == 0u) {
                    __builtin_amdgcn_s_sleep(2);
                }
                contflag = (int)fv;
                if (fv == 1u) {
                    for (int i = 0; i < 12; ++i)
                        st[b][i] = __hip_atomic_load(&stpub[step*32 + b*16 + i],
                                                     __ATOMIC_RELAXED,
                                                     __HIP_MEMORY_SCOPE_AGENT);
                }
            }
            __syncthreads();
        }
        if (contflag == 2) break;   // uniform across the grid
    }

    if (bid == 0 && tid < 2) {
        float r00 = st[tid][0], r01 = st[tid][1], r02 = st[tid][2];
        float r10 = st[tid][3], r11 = st[tid][4], r12 = st[tid][5];
        float r20 = st[tid][6], r21 = st[tid][7], r22 = st[tid][8];
        float qw = 0.5f * sqrtf(fmaxf(1.f + r00 + r11 + r22, 1e-12f));
        float qx = 0.5f * sqrtf(fmaxf(1.f + r00 - r11 - r22, 1e-12f));
        float qy = 0.5f * sqrtf(fmaxf(1.f - r00 + r11 - r22, 1e-12f));
        float qz = 0.5f * sqrtf(fmaxf(1.f - r00 - r11 + r22, 1e-12f));
        qx = (r21 - r12 >= 0.f) ? qx : -qx;
        qy = (r02 - r20 >= 0.f) ? qy : -qy;
        qz = (r10 - r01 >= 0.f) ? qz : -qz;
        out[tid * 7 + 0] = st[tid][9];
        out[tid * 7 + 1] = st[tid][10];
        out[tid * 7 + 2] = st[tid][11];
        out[tid * 7 + 3] = qx;
        out[tid * 7 + 4] = qy;
        out[tid * 7 + 5] = qz;
        out[tid * 7 + 6] = qw;
    }
}

extern "C" void kernel_launch(void* const* d_in, const int* in_sizes, int n_in,
                              void* d_out, int out_size, void* d_ws, size_t ws_size,
                              hipStream_t stream) {
    const float* psrc = (const float*)d_in[0];
    const float* ptgt = (const float*)d_in[1];
    float* out = (float*)d_out;
    float* ws = (float*)d_ws;

    init_kernel<<<32, 256, 0, stream>>>(ptgt, ws);
    icp_main<<<NBLK, 512, 0, stream>>>(psrc, ws, out);
}

// Round 17
// 189.239 us; speedup vs baseline: 1.0934x; 1.0283x over previous
//
#include <hip/hip_runtime.h>
#include <math.h>

#define NPTS 4096
#define MPTS 4096
#define NSTEPS 8
#define ICP_TOL 1e-6f
#define NBLK 256    // 1 block/CU: residency guaranteed -> barrier can't deadlock (R16-proven)

// ws layout (floats):
//   ptgt4 : [0, 32768)       interleaved {x,y,z,0.5*|t|^2}, 2*4096 targets
//   acc   : [32768, 65536)   [step][block(256)][16] per-block partials (atomic stores)
//   ctrs  : words at 98304, stride 1024/step:
//             domain-b subs at (b*8+c)*16 (c<8, 16 blocks each)
//             domain-b master ctr at 256 + b*16
//             domain-b flags at 512 + b*256 + f*16 (f<16); 0=wait,1=continue,2=converged
//   stpub : floats at 110592, 32/step: [step][batch][16] published R(9)+t(3)
#define ACC_OFF 32768
#define CTR_OFF 98304
#define CTR_STRIDE 1024
#define STPUB_OFF 110592

__global__ void init_kernel(const float* __restrict__ ptgt, float* __restrict__ ws) {
    float* ptgt4 = ws;
    unsigned* ctrs = (unsigned*)(ws + CTR_OFF);
    int gid = blockIdx.x * 256 + threadIdx.x;   // 8192 threads
    if (gid < 2 * MPTS) {
        float x = ptgt[3 * gid + 0];
        float y = ptgt[3 * gid + 1];
        float z = ptgt[3 * gid + 2];
        float4 v;
        v.x = x; v.y = y; v.z = z;
        v.w = 0.5f * (x * x + y * y + z * z);
        ((float4*)ptgt4)[gid] = v;
    }
    for (int i = gid; i < NSTEPS * CTR_STRIDE; i += 8192) ctrs[i] = 0u;
}

__device__ __forceinline__ float frcp(float x) {
#if __has_builtin(__builtin_amdgcn_rcpf)
    return __builtin_amdgcn_rcpf(x);
#else
    return 1.f / x;
#endif
}
__device__ __forceinline__ float frsq(float x) {
#if __has_builtin(__builtin_amdgcn_rsqf)
    return __builtin_amdgcn_rsqf(x);
#else
    return 1.f / sqrtf(x);
#endif
}

#define DET3(a,b,c,d,e,f,g,h,i) \
    ((a)*((e)*(i)-(f)*(h)) - (b)*((d)*(i)-(f)*(g)) + (c)*((d)*(h)-(e)*(g)))

// Max-eigenpair of symmetric 4x4: Newton on characteristic quartic from a
// Gershgorin upper bound + cofactor-row eigenvector. ~1200-cyc serial chain.
__device__ __forceinline__ void horn_quat(const float N[4][4], float q[4]) {
    float s = 1e-30f;
#pragma unroll
    for (int i = 0; i < 4; ++i)
#pragma unroll
        for (int j = 0; j < 4; ++j) s = fmaxf(s, fabsf(N[i][j]));
    float inv = frcp(s);
    float A[4][4], B[4][4];
#pragma unroll
    for (int i = 0; i < 4; ++i)
#pragma unroll
        for (int j = 0; j < 4; ++j) A[i][j] = N[i][j] * inv;
#pragma unroll
    for (int i = 0; i < 4; ++i)
#pragma unroll
        for (int j = i; j < 4; ++j) {
            float v = A[i][0]*A[0][j] + A[i][1]*A[1][j] + A[i][2]*A[2][j] + A[i][3]*A[3][j];
            B[i][j] = v; B[j][i] = v;
        }
    float p1 = A[0][0]+A[1][1]+A[2][2]+A[3][3];
    float p2 = B[0][0]+B[1][1]+B[2][2]+B[3][3];
    float p3 = 0.f, p4 = 0.f;
#pragma unroll
    for (int i = 0; i < 4; ++i)
#pragma unroll
        for (int j = 0; j < 4; ++j) { p3 += A[i][j]*B[i][j]; p4 += B[i][j]*B[i][j]; }
    float e1 = p1;
    float e2 = 0.5f*(e1*p1 - p2);
    float e3 = (e2*p1 - e1*p2 + p3)*(1.f/3.f);
    float e4 = 0.25f*(e3*p1 - e2*p2 + e1*p3 - p4);
    float lam = -3e38f;
#pragma unroll
    for (int i = 0; i < 4; ++i) {
        float r = A[i][i];
#pragma unroll
        for (int j = 0; j < 4; ++j) if (j != i) r += fabsf(A[i][j]);
        lam = fmaxf(lam, r);
    }
#pragma unroll
    for (int it = 0; it < 12; ++it) {
        float pv = (((lam - e1)*lam + e2)*lam - e3)*lam + e4;
        float dv = ((4.f*lam - 3.f*e1)*lam + 2.f*e2)*lam - e3;
        lam -= pv * frcp(dv);
    }
    float M[4][4];
#pragma unroll
    for (int i = 0; i < 4; ++i)
#pragma unroll
        for (int j = 0; j < 4; ++j) M[i][j] = A[i][j] - ((i == j) ? lam : 0.f);
    float C0 = DET3(M[1][1],M[1][2],M[1][3], M[2][1],M[2][2],M[2][3], M[3][1],M[3][2],M[3][3]);
    float C1 = DET3(M[0][0],M[0][2],M[0][3], M[2][0],M[2][2],M[2][3], M[3][0],M[3][2],M[3][3]);
    float C2 = DET3(M[0][0],M[0][1],M[0][3], M[1][0],M[1][1],M[1][3], M[3][0],M[3][1],M[3][3]);
    float C3 = DET3(M[0][0],M[0][1],M[0][2], M[1][0],M[1][1],M[1][2], M[2][0],M[2][1],M[2][2]);
    int is = 0; float cb = fabsf(C0);
    if (fabsf(C1) > cb) { cb = fabsf(C1); is = 1; }
    if (fabsf(C2) > cb) { cb = fabsf(C2); is = 2; }
    if (fabsf(C3) > cb) { cb = fabsf(C3); is = 3; }
    float v0, v1, v2, v3;
#define ROWCOF(a,b,c) { \
    v0 =  DET3(M[a][1],M[a][2],M[a][3], M[b][1],M[b][2],M[b][3], M[c][1],M[c][2],M[c][3]); \
    v1 = -DET3(M[a][0],M[a][2],M[a][3], M[b][0],M[b][2],M[b][3], M[c][0],M[c][2],M[c][3]); \
    v2 =  DET3(M[a][0],M[a][1],M[a][3], M[b][0],M[b][1],M[b][3], M[c][0],M[c][1],M[c][3]); \
    v3 = -DET3(M[a][0],M[a][1],M[a][2], M[b][0],M[b][1],M[b][2], M[c][0],M[c][1],M[c][2]); }
    if (is == 0)      ROWCOF(1,2,3)
    else if (is == 1) ROWCOF(0,2,3)
    else if (is == 2) ROWCOF(0,1,3)
    else              ROWCOF(0,1,2)
#undef ROWCOF
    float nr = frsq(v0*v0 + v1*v1 + v2*v2 + v3*v3);
    q[0] = v0*nr; q[1] = v1*nr; q[2] = v2*nr; q[3] = v3*nr;
}

#define FOR16(OP) OP(0) OP(1) OP(2) OP(3) OP(4) OP(5) OP(6) OP(7) \
                  OP(8) OP(9) OP(10) OP(11) OP(12) OP(13) OP(14) OP(15)

// 256 blocks x 512 threads, persistent, 1 block/CU. Targets + block's 32
// source points staged in LDS once per kernel. TWO independent sync domains
// (one per batch, masters = blocks 0 and 128): per step each master waits on
// 128 arrivals, float4-gathers its 128 slots, Horn-solves, publishes R,t +
// flag (1+conv_b); every block reads BOTH domains' flags (parallel spin
// waves) and applies iff !(conv0 && conv1) — faithful to the reference's
// cross-batch convergence AND. Fence-free agent-atomic pattern (R5-R16).
__global__ __launch_bounds__(512, 2) void icp_main(
    const float* __restrict__ psrc, float* __restrict__ ws,
    float* __restrict__ out) {

    float* ptgt4 = ws;
    float* acc = ws + ACC_OFF;
    unsigned* ctrs = (unsigned*)(ws + CTR_OFF);
    float* stpub = ws + STPUB_OFF;

    __shared__ float tshx[MPTS];    // 16 KB
    __shared__ float tshy[MPTS];    // 16 KB
    __shared__ float tshz[MPTS];    // 16 KB
    __shared__ float spx[32], spy[32], spz[32];   // block's source points
    __shared__ float stq[13];       // this batch: Rcum(9), tcum(3), err(1)
    __shared__ unsigned keys[8][16];
    __shared__ float red[16][16];
    __shared__ float gd[16][132];   // master gather [comp][slot] (+pad)
    __shared__ float gp[4][16];     // partial sums
    __shared__ float asum[16];
    __shared__ float stv[12];       // worker-received R,t
    __shared__ int fvs[2];          // this-domain flag, other-domain flag

    const int tid = threadIdx.x;
    const int bid = blockIdx.x;
    const int b = bid >> 7;             // batch / sync domain (128 blocks each)
    const int n0 = (bid & 127) * 32;    // this block's 32 source points

    // ---- one-time staging ----
    {
        const float4* tp4 = (const float4*)ptgt4 + (size_t)b * MPTS;
        for (int i = tid; i < MPTS; i += 512) {
            float4 v = tp4[i];
            tshx[i] = v.x; tshy[i] = v.y; tshz[i] = v.z;
        }
    }
    if (tid < 32) {
        const float* pp = psrc + ((size_t)b * NPTS + n0 + tid) * 3;
        spx[tid] = pp[0]; spy[tid] = pp[1]; spz[tid] = pp[2];
    }
    if (tid == 0) {
        stq[0] = 1.f; stq[1] = 0.f; stq[2] = 0.f;
        stq[3] = 0.f; stq[4] = 1.f; stq[5] = 0.f;
        stq[6] = 0.f; stq[7] = 0.f; stq[8] = 1.f;
        stq[9] = 0.f; stq[10] = 0.f; stq[11] = 0.f;
        stq[12] = 0.f;
    }
    __syncthreads();

    const int w = tid >> 6, lane = tid & 63;   // w in 0..7
    const int m0 = w * 512 + lane;
    bool done = false;

    for (int step = 0; step < NSTEPS; ++step) {
        float R00 = stq[0], R01 = stq[1], R02 = stq[2];
        float R10 = stq[3], R11 = stq[4], R12 = stq[5];
        float R20 = stq[6], R21 = stq[7], R22 = stq[8];
        float t0 = stq[9], t1 = stq[10], t2 = stq[11];

        float sacc = 0.f;   // per-component accumulator (tid<16)

        for (int p = 0; p < 2; ++p) {
            const int np = p * 16;

#define DECLP(i) float px##i, py##i, pz##i;
            FOR16(DECLP)
#undef DECLP
#define LOADP(i) { float x = spx[np+(i)], y = spy[np+(i)], z = spz[np+(i)]; \
            px##i = fmaf(R00, x, fmaf(R01, y, fmaf(R02, z, t0))); \
            py##i = fmaf(R10, x, fmaf(R11, y, fmaf(R12, z, t1))); \
            pz##i = fmaf(R20, x, fmaf(R21, y, fmaf(R22, z, t2))); }
            FOR16(LOADP)
#undef LOADP

            // s = p.t - |t|^2/2; argmax s == argmin dist
#define DECLB(i) float bs##i = -3.0e38f; int ix##i = m0;
            FOR16(DECLB)
#undef DECLB

            float tcx = tshx[m0], tcy = tshy[m0], tcz = tshz[m0];
            int mreg = m0;
#pragma unroll
            for (int k = 0; k < 8; ++k) {
                int mn = m0 + ((k + 1) & 7) * 64;   // next-iter prefetch (wraps)
                float tnx = tshx[mn], tny = tshy[mn], tnz = tshz[mn];
                float htn = 0.5f * (tcx * tcx + tcy * tcy + tcz * tcz);
                float tx = tcx, ty = tcy, tz = tcz;
#define PAIR(i) { float s = fmaf(px##i, tx, fmaf(py##i, ty, fmaf(pz##i, tz, -htn))); \
                if (s > bs##i) { bs##i = s; ix##i = mreg; } }
                FOR16(PAIR)
#undef PAIR
                mreg += 64;
                tcx = tnx; tcy = tny; tcz = tnz;
            }

            // wave argmax via order-preserving packed key: score hi-20 | (4095-m)
#define REDKEY(i) { unsigned ub = __float_as_uint(bs##i); \
            unsigned u = ((int)ub >= 0) ? (ub | 0x80000000u) : ~ub; \
            unsigned key = (u & 0xFFFFF000u) | (4095u - (unsigned)ix##i); \
            for (int off = 32; off; off >>= 1) { \
                unsigned o = (unsigned)__shfl_xor((int)key, off); \
                key = key > o ? key : o; } \
            if (lane == 0) keys[w][i] = key; }
            FOR16(REDKEY)
#undef REDKEY
            __syncthreads();

            if (tid < 16) {
                unsigned key = keys[0][tid];
#pragma unroll
                for (int ww = 1; ww < 8; ++ww) {
                    unsigned o = keys[ww][tid];
                    key = key > o ? key : o;
                }
                int m = 4095 - (int)(key & 0xFFFu);
                float qx2 = tshx[m], qy2 = tshy[m], qz2 = tshz[m];
                float x = spx[np + tid], y = spy[np + tid], z = spz[np + tid];
                float px = fmaf(R00, x, fmaf(R01, y, fmaf(R02, z, t0)));
                float py = fmaf(R10, x, fmaf(R11, y, fmaf(R12, z, t1)));
                float pz = fmaf(R20, x, fmaf(R21, y, fmaf(R22, z, t2)));
                float dx = px - qx2, dy = py - qy2, dz = pz - qz2;
                float dist = sqrtf(dx * dx + dy * dy + dz * dz);
                red[tid][0] = px; red[tid][1] = py; red[tid][2] = pz;
                red[tid][3] = qx2; red[tid][4] = qy2; red[tid][5] = qz2;
                red[tid][6] = px * qx2;  red[tid][7] = px * qy2;  red[tid][8] = px * qz2;
                red[tid][9] = py * qx2;  red[tid][10] = py * qy2; red[tid][11] = py * qz2;
                red[tid][12] = pz * qx2; red[tid][13] = pz * qy2; red[tid][14] = pz * qz2;
                red[tid][15] = dist;
            }
            __syncthreads();
            if (tid < 16) {
                float s = 0.f;
#pragma unroll
                for (int r = 0; r < 16; ++r) s += red[r][tid];
                sacc += s;
            }
            __syncthreads();   // keys/red reused next pass
        }

        if (tid < 16) {
            __hip_atomic_store(&acc[((size_t)step * NBLK + bid) * 16 + tid], sacc,
                               __ATOMIC_RELAXED, __HIP_MEMORY_SCOPE_AGENT);
        }

        // ---- arrival (per domain), then master/worker split ----
        unsigned* stepc = ctrs + step * CTR_STRIDE;
        __syncthreads();   // drains the acc stores before arrival RMW
        if (tid == 0) {
            unsigned* sub = stepc + (b * 8 + (bid & 7)) * 16;
            unsigned old = __hip_atomic_fetch_add(sub, 1u, __ATOMIC_RELAXED,
                                                  __HIP_MEMORY_SCOPE_AGENT);
            if (old == 15u)
                __hip_atomic_fetch_add(stepc + 256 + b * 16, 1u, __ATOMIC_RELAXED,
                                       __HIP_MEMORY_SCOPE_AGENT);
        }

        const bool is_master = ((bid & 127) == 0);
        if (is_master) {
            if (tid == 0) {
                while (__hip_atomic_load(stepc + 256 + b * 16, __ATOMIC_RELAXED,
                                         __HIP_MEMORY_SCOPE_AGENT) < 8u) {
                    __builtin_amdgcn_s_sleep(1);
                }
            }
            __syncthreads();
            // float4 gather: 128 slots x 16 comps = 1 float4 per thread
            {
                int s = tid >> 2, cb = (tid & 3) * 4;
                const float* base = acc + ((size_t)step * NBLK + b * 128 + s) * 16 + cb;
                float4 v = *(const float4*)base;
                gd[cb + 0][s] = v.x;
                gd[cb + 1][s] = v.y;
                gd[cb + 2][s] = v.z;
                gd[cb + 3][s] = v.w;
            }
            __syncthreads();
            if (tid < 64) {
                int c = tid & 15, part = tid >> 4;   // 4 parts x 32 slots
                float s = 0.f;
#pragma unroll
                for (int i = 0; i < 32; ++i) s += gd[c][part * 32 + i];
                gp[part][c] = s;
            }
            __syncthreads();
            if (tid < 16) asum[tid] = gp[0][tid] + gp[1][tid] + gp[2][tid] + gp[3][tid];
            __syncthreads();

            if (tid == 0) {
                float a[16];
                for (int i = 0; i < 16; ++i) a[i] = asum[i];
                float errnew = a[15] * (1.f / NPTS);
                bool conv_b = (fabsf(errnew - stq[12]) < ICP_TOL);

                const float inv_n = 1.f / NPTS;
                float pmx = a[0]*inv_n, pmy = a[1]*inv_n, pmz = a[2]*inv_n;
                float qmx = a[3]*inv_n, qmy = a[4]*inv_n, qmz = a[5]*inv_n;
                float H[3][3];
                for (int i = 0; i < 3; ++i)
                    for (int j = 0; j < 3; ++j)
                        H[i][j] = a[6 + 3*i + j] - a[i]*a[3 + j]*inv_n;
                float Sxx=H[0][0], Sxy=H[0][1], Sxz=H[0][2];
                float Syx=H[1][0], Syy=H[1][1], Syz=H[1][2];
                float Szx=H[2][0], Szy=H[2][1], Szz=H[2][2];
                float Nm[4][4];
                Nm[0][0] = Sxx+Syy+Szz; Nm[0][1] = Syz-Szy;
                Nm[0][2] = Szx-Sxz;     Nm[0][3] = Sxy-Syx;
                Nm[1][1] = Sxx-Syy-Szz; Nm[1][2] = Sxy+Syx; Nm[1][3] = Szx+Sxz;
                Nm[2][2] = -Sxx+Syy-Szz; Nm[2][3] = Syz+Szy;
                Nm[3][3] = -Sxx-Syy+Szz;
                Nm[1][0]=Nm[0][1]; Nm[2][0]=Nm[0][2]; Nm[3][0]=Nm[0][3];
                Nm[2][1]=Nm[1][2]; Nm[3][1]=Nm[1][3]; Nm[3][2]=Nm[2][3];
                float qv[4];
                horn_quat(Nm, qv);
                float qw = qv[0], qx = qv[1], qy = qv[2], qz = qv[3];
                float R00n = 1.f - 2.f*(qy*qy + qz*qz);
                float R01n = 2.f*(qx*qy - qw*qz);
                float R02n = 2.f*(qx*qz + qw*qy);
                float R10n = 2.f*(qx*qy + qw*qz);
                float R11n = 1.f - 2.f*(qx*qx + qz*qz);
                float R12n = 2.f*(qy*qz - qw*qx);
                float R20n = 2.f*(qx*qz - qw*qy);
                float R21n = 2.f*(qy*qz + qw*qx);
                float R22n = 1.f - 2.f*(qx*qx + qy*qy);
                float tx = qmx - (R00n*pmx + R01n*pmy + R02n*pmz);
                float ty = qmy - (R10n*pmx + R11n*pmy + R12n*pmz);
                float tz = qmz - (R20n*pmx + R21n*pmy + R22n*pmz);
                float C00=stq[0], C01=stq[1], C02=stq[2];
                float C10=stq[3], C11=stq[4], C12=stq[5];
                float C20=stq[6], C21=stq[7], C22=stq[8];
                float T0=stq[9], T1=stq[10], T2=stq[11];
                float ns[12];
                ns[0] = R00n*C00 + R01n*C10 + R02n*C20;
                ns[1] = R00n*C01 + R01n*C11 + R02n*C21;
                ns[2] = R00n*C02 + R01n*C12 + R02n*C22;
                ns[3] = R10n*C00 + R11n*C10 + R12n*C20;
                ns[4] = R10n*C01 + R11n*C11 + R12n*C21;
                ns[5] = R10n*C02 + R11n*C12 + R12n*C22;
                ns[6] = R20n*C00 + R21n*C10 + R22n*C20;
                ns[7] = R20n*C01 + R21n*C11 + R22n*C21;
                ns[8] = R20n*C02 + R21n*C12 + R22n*C22;
                ns[9]  = R00n*T0 + R01n*T1 + R02n*T2 + tx;
                ns[10] = R10n*T0 + R11n*T1 + R12n*T2 + ty;
                ns[11] = R20n*T0 + R21n*T1 + R22n*T2 + tz;
                for (int i = 0; i < 12; ++i) {
                    stv[i] = ns[i];
                    __hip_atomic_store(&stpub[step*32 + b*16 + i], ns[i],
                                       __ATOMIC_RELAXED, __HIP_MEMORY_SCOPE_AGENT);
                }
                stv[0] = ns[0];   // stv holds pending update for later apply
                for (int i = 0; i < 12; ++i) stv[i] = ns[i];
                asum[15] = errnew;   // stash for conditional err update
                fvs[b] = 1 + (conv_b ? 1 : 0);
            }
            __syncthreads();   // drains stpub stores before flag release
            if (tid == 0) {
                unsigned fv = (unsigned)fvs[b];
#pragma unroll
                for (int f = 0; f < 16; ++f)
                    __hip_atomic_store(stepc + 512 + b * 256 + f * 16, fv,
                                       __ATOMIC_RELAXED, __HIP_MEMORY_SCOPE_AGENT);
            }
            // poll OTHER domain's flag (after publishing own: no deadlock)
            if (tid == 64) {
                unsigned* of = stepc + 512 + (1 - b) * 256;
                unsigned fv;
                while ((fv = __hip_atomic_load(of, __ATOMIC_RELAXED,
                                               __HIP_MEMORY_SCOPE_AGENT)) == 0u) {
                    __builtin_amdgcn_s_sleep(1);
                }
                fvs[1 - b] = (int)fv;
            }
            __syncthreads();
            bool conv = (fvs[0] == 2) && (fvs[1] == 2);
            bool done_new = done || conv;
            if (tid == 0 && !done_new) {
                for (int i = 0; i < 12; ++i) stq[i] = stv[i];
                stq[12] = asum[15];
            }
            __syncthreads();
            done = done_new;
        } else {
            // workers: two parallel spin waves (own flag, other flag)
            if (tid == 0) {
                unsigned* mf = stepc + 512 + b * 256 + (bid & 15) * 16;
                unsigned fv;
                while ((fv = __hip_atomic_load(mf, __ATOMIC_RELAXED,
                                               __HIP_MEMORY_SCOPE_AGENT)) == 0u) {
                    __builtin_amdgcn_s_sleep(1);
                }
                fvs[b] = (int)fv;
            }
            if (tid == 64) {
                unsigned* of = stepc + 512 + (1 - b) * 256 + (bid & 15) * 16;
                unsigned fv;
                while ((fv = __hip_atomic_load(of, __ATOMIC_RELAXED,
                                               __HIP_MEMORY_SCOPE_AGENT)) == 0u) {
                    __builtin_amdgcn_s_sleep(1);
                }
                fvs[1 - b] = (int)fv;
            }
            __syncthreads();
            if (tid < 12) {
                stv[tid] = __hip_atomic_load(&stpub[step*32 + b*16 + tid],
                                             __ATOMIC_RELAXED,
                                             __HIP_MEMORY_SCOPE_AGENT);
            }
            __syncthreads();
            bool conv = (fvs[0] == 2) && (fvs[1] == 2);
            bool done_new = done || conv;
            if (tid < 12 && !done_new) stq[tid] = stv[tid];
            __syncthreads();
            done = done_new;
        }
        if (done) break;   // uniform across the grid (same flag values everywhere)
    }

    if ((bid == 0 || bid == 128) && tid == 0) {
        float r00 = stq[0], r01 = stq[1], r02 = stq[2];
        float r10 = stq[3], r11 = stq[4], r12 = stq[5];
        float r20 = stq[6], r21 = stq[7], r22 = stq[8];
        float qw = 0.5f * sqrtf(fmaxf(1.f + r00 + r11 + r22, 1e-12f));
        float qx = 0.5f * sqrtf(fmaxf(1.f + r00 - r11 - r22, 1e-12f));
        float qy = 0.5f * sqrtf(fmaxf(1.f - r00 + r11 - r22, 1e-12f));
        float qz = 0.5f * sqrtf(fmaxf(1.f - r00 - r11 + r22, 1e-12f));
        qx = (r21 - r12 >= 0.f) ? qx : -qx;
        qy = (r02 - r20 >= 0.f) ? qy : -qy;
        qz = (r10 - r01 >= 0.f) ? qz : -qz;
        out[b * 7 + 0] = stq[9];
        out[b * 7 + 1] = stq[10];
        out[b * 7 + 2] = stq[11];
        out[b * 7 + 3] = qx;
        out[b * 7 + 4] = qy;
        out[b * 7 + 5] = qz;
        out[b * 7 + 6] = qw;
    }
}

extern "C" void kernel_launch(void* const* d_in, const int* in_sizes, int n_in,
                              void* d_out, int out_size, void* d_ws, size_t ws_size,
                              hipStream_t stream) {
    const float* psrc = (const float*)d_in[0];
    const float* ptgt = (const float*)d_in[1];
    float* out = (float*)d_out;
    float* ws = (float*)d_ws;

    init_kernel<<<32, 256, 0, stream>>>(ptgt, ws);
    icp_main<<<NBLK, 512, 0, stream>>>(psrc, ws, out);
}

// Round 18
// 185.819 us; speedup vs baseline: 1.1135x; 1.0184x over previous
//
#include <hip/hip_runtime.h>
#include <math.h>

#define NPTS 4096
#define MPTS 4096
#define NSTEPS 8
#define ICP_TOL 1e-6f
#define NBLK 256    // 1 block/CU: all blocks resident -> sentinel dataflow can't deadlock
#define SENT 0x7FBADBADu   // NaN bit pattern: unreachable by any finite-input float sum

// ws layout (floats):
//   ptgt4 : [0, 32768)       interleaved {x,y,z,0.5*|t|^2}, 2*4096 targets
//   acc   : [32768, 65536)   [step][block(256)][16] per-block partials.
//           Pre-filled with SENT by init_kernel; a slot's 16 words become
//           valid exactly when its producer's atomic stores land. The slots
//           ARE the synchronization (no counters, no flags, no barrier).
#define ACC_OFF 32768

__global__ void init_kernel(const float* __restrict__ ptgt, float* __restrict__ ws) {
    float* ptgt4 = ws;
    unsigned* accu = (unsigned*)(ws + ACC_OFF);
    int gid = blockIdx.x * 256 + threadIdx.x;   // 8192 threads
    if (gid < 2 * MPTS) {
        float x = ptgt[3 * gid + 0];
        float y = ptgt[3 * gid + 1];
        float z = ptgt[3 * gid + 2];
        float4 v;
        v.x = x; v.y = y; v.z = z;
        v.w = 0.5f * (x * x + y * y + z * z);
        ((float4*)ptgt4)[gid] = v;
    }
    for (int i = gid; i < NSTEPS * NBLK * 16; i += 8192) accu[i] = SENT;
}

__device__ __forceinline__ float frcp(float x) {
#if __has_builtin(__builtin_amdgcn_rcpf)
    return __builtin_amdgcn_rcpf(x);
#else
    return 1.f / x;
#endif
}
__device__ __forceinline__ float frsq(float x) {
#if __has_builtin(__builtin_amdgcn_rsqf)
    return __builtin_amdgcn_rsqf(x);
#else
    return 1.f / sqrtf(x);
#endif
}

__device__ __forceinline__ float poll_word(const unsigned* p) {
    unsigned v;
    while ((v = __hip_atomic_load(p, __ATOMIC_RELAXED,
                                  __HIP_MEMORY_SCOPE_AGENT)) == SENT) {
        __builtin_amdgcn_s_sleep(1);
    }
    return __uint_as_float(v);
}

#define DET3(a,b,c,d,e,f,g,h,i) \
    ((a)*((e)*(i)-(f)*(h)) - (b)*((d)*(i)-(f)*(g)) + (c)*((d)*(h)-(e)*(g)))

// Max-eigenpair of symmetric 4x4: Newton on characteristic quartic from a
// Gershgorin upper bound + cofactor-row eigenvector. ~1200-cyc serial chain.
__device__ __forceinline__ void horn_quat(const float N[4][4], float q[4]) {
    float s = 1e-30f;
#pragma unroll
    for (int i = 0; i < 4; ++i)
#pragma unroll
        for (int j = 0; j < 4; ++j) s = fmaxf(s, fabsf(N[i][j]));
    float inv = frcp(s);
    float A[4][4], B[4][4];
#pragma unroll
    for (int i = 0; i < 4; ++i)
#pragma unroll
        for (int j = 0; j < 4; ++j) A[i][j] = N[i][j] * inv;
#pragma unroll
    for (int i = 0; i < 4; ++i)
#pragma unroll
        for (int j = i; j < 4; ++j) {
            float v = A[i][0]*A[0][j] + A[i][1]*A[1][j] + A[i][2]*A[2][j] + A[i][3]*A[3][j];
            B[i][j] = v; B[j][i] = v;
        }
    float p1 = A[0][0]+A[1][1]+A[2][2]+A[3][3];
    float p2 = B[0][0]+B[1][1]+B[2][2]+B[3][3];
    float p3 = 0.f, p4 = 0.f;
#pragma unroll
    for (int i = 0; i < 4; ++i)
#pragma unroll
        for (int j = 0; j < 4; ++j) { p3 += A[i][j]*B[i][j]; p4 += B[i][j]*B[i][j]; }
    float e1 = p1;
    float e2 = 0.5f*(e1*p1 - p2);
    float e3 = (e2*p1 - e1*p2 + p3)*(1.f/3.f);
    float e4 = 0.25f*(e3*p1 - e2*p2 + e1*p3 - p4);
    float lam = -3e38f;
#pragma unroll
    for (int i = 0; i < 4; ++i) {
        float r = A[i][i];
#pragma unroll
        for (int j = 0; j < 4; ++j) if (j != i) r += fabsf(A[i][j]);
        lam = fmaxf(lam, r);
    }
#pragma unroll
    for (int it = 0; it < 12; ++it) {
        float pv = (((lam - e1)*lam + e2)*lam - e3)*lam + e4;
        float dv = ((4.f*lam - 3.f*e1)*lam + 2.f*e2)*lam - e3;
        lam -= pv * frcp(dv);
    }
    float M[4][4];
#pragma unroll
    for (int i = 0; i < 4; ++i)
#pragma unroll
        for (int j = 0; j < 4; ++j) M[i][j] = A[i][j] - ((i == j) ? lam : 0.f);
    float C0 = DET3(M[1][1],M[1][2],M[1][3], M[2][1],M[2][2],M[2][3], M[3][1],M[3][2],M[3][3]);
    float C1 = DET3(M[0][0],M[0][2],M[0][3], M[2][0],M[2][2],M[2][3], M[3][0],M[3][2],M[3][3]);
    float C2 = DET3(M[0][0],M[0][1],M[0][3], M[1][0],M[1][1],M[1][3], M[3][0],M[3][1],M[3][3]);
    float C3 = DET3(M[0][0],M[0][1],M[0][2], M[1][0],M[1][1],M[1][2], M[2][0],M[2][1],M[2][2]);
    int is = 0; float cb = fabsf(C0);
    if (fabsf(C1) > cb) { cb = fabsf(C1); is = 1; }
    if (fabsf(C2) > cb) { cb = fabsf(C2); is = 2; }
    if (fabsf(C3) > cb) { cb = fabsf(C3); is = 3; }
    float v0, v1, v2, v3;
#define ROWCOF(a,b,c) { \
    v0 =  DET3(M[a][1],M[a][2],M[a][3], M[b][1],M[b][2],M[b][3], M[c][1],M[c][2],M[c][3]); \
    v1 = -DET3(M[a][0],M[a][2],M[a][3], M[b][0],M[b][2],M[b][3], M[c][0],M[c][2],M[c][3]); \
    v2 =  DET3(M[a][0],M[a][1],M[a][3], M[b][0],M[b][1],M[b][3], M[c][0],M[c][1],M[c][3]); \
    v3 = -DET3(M[a][0],M[a][1],M[a][2], M[b][0],M[b][1],M[b][2], M[c][0],M[c][1],M[c][2]); }
    if (is == 0)      ROWCOF(1,2,3)
    else if (is == 1) ROWCOF(0,2,3)
    else if (is == 2) ROWCOF(0,1,3)
    else              ROWCOF(0,1,2)
#undef ROWCOF
    float nr = frsq(v0*v0 + v1*v1 + v2*v2 + v3*v3);
    q[0] = v0*nr; q[1] = v1*nr; q[2] = v2*nr; q[3] = v3*nr;
}

#define FOR16(OP) OP(0) OP(1) OP(2) OP(3) OP(4) OP(5) OP(6) OP(7) \
                  OP(8) OP(9) OP(10) OP(11) OP(12) OP(13) OP(14) OP(15)

// 256 blocks x 512 threads, persistent, 1 block/CU. Targets + 32 source pts
// in LDS once per kernel. Per step: NN (2x16-point passes, wave w scans
// 512-target slice) -> per-block private atomic stores into SENT-prefilled
// slots -> EVERY block polls the slots directly (sentinel = arrival signal;
// no counters/flags/barrier) -> fixed-order LDS reduce -> redundant Newton
// solve. Convergence err sums use one fixed reduction order identical in all
// blocks -> bit-identical done decisions -> uniform termination (no hang).
__global__ __launch_bounds__(512, 2) void icp_main(
    const float* __restrict__ psrc, float* __restrict__ ws,
    float* __restrict__ out) {

    float* acc = ws + ACC_OFF;

    __shared__ float tshx[MPTS];    // 16 KB
    __shared__ float tshy[MPTS];    // 16 KB
    __shared__ float tshz[MPTS];    // 16 KB
    __shared__ float spx[32], spy[32], spz[32];   // block's source points
    __shared__ float stq[13];       // own batch: Rcum(9), tcum(3), [12] unused
    __shared__ float st_err[2];     // both batches' latched errs
    __shared__ unsigned keys[8][16];
    __shared__ float red[16][16];
    __shared__ float gd[16][132];   // polled own-batch slots [comp][slot]
    __shared__ float gp[4][16];
    __shared__ float asum[16];
    __shared__ float e0[128], e1[128], ep0[32], ep1[32];
    __shared__ int doneLDS;

    const int tid = threadIdx.x;
    const int bid = blockIdx.x;
    const int b = bid >> 7;             // batch (128 blocks each)
    const int n0 = (bid & 127) * 32;    // this block's 32 source points

    // ---- one-time staging ----
    {
        const float4* tp4 = (const float4*)ws + (size_t)b * MPTS;
        for (int i = tid; i < MPTS; i += 512) {
            float4 v = tp4[i];
            tshx[i] = v.x; tshy[i] = v.y; tshz[i] = v.z;
        }
    }
    if (tid < 32) {
        const float* pp = psrc + ((size_t)b * NPTS + n0 + tid) * 3;
        spx[tid] = pp[0]; spy[tid] = pp[1]; spz[tid] = pp[2];
    }
    if (tid == 0) {
        stq[0] = 1.f; stq[1] = 0.f; stq[2] = 0.f;
        stq[3] = 0.f; stq[4] = 1.f; stq[5] = 0.f;
        stq[6] = 0.f; stq[7] = 0.f; stq[8] = 1.f;
        stq[9] = 0.f; stq[10] = 0.f; stq[11] = 0.f;
        st_err[0] = 0.f; st_err[1] = 0.f;
    }
    __syncthreads();

    const int w = tid >> 6, lane = tid & 63;   // w in 0..7
    const int m0 = w * 512 + lane;

    for (int step = 0; step < NSTEPS; ++step) {
        float R00 = stq[0], R01 = stq[1], R02 = stq[2];
        float R10 = stq[3], R11 = stq[4], R12 = stq[5];
        float R20 = stq[6], R21 = stq[7], R22 = stq[8];
        float t0 = stq[9], t1 = stq[10], t2 = stq[11];

        float sacc = 0.f;   // per-component accumulator (tid<16)

        for (int p = 0; p < 2; ++p) {
            const int np = p * 16;

#define DECLP(i) float px##i, py##i, pz##i;
            FOR16(DECLP)
#undef DECLP
#define LOADP(i) { float x = spx[np+(i)], y = spy[np+(i)], z = spz[np+(i)]; \
            px##i = fmaf(R00, x, fmaf(R01, y, fmaf(R02, z, t0))); \
            py##i = fmaf(R10, x, fmaf(R11, y, fmaf(R12, z, t1))); \
            pz##i = fmaf(R20, x, fmaf(R21, y, fmaf(R22, z, t2))); }
            FOR16(LOADP)
#undef LOADP

            // s = p.t - |t|^2/2; argmax s == argmin dist
#define DECLB(i) float bs##i = -3.0e38f; int ix##i = m0;
            FOR16(DECLB)
#undef DECLB

            float tcx = tshx[m0], tcy = tshy[m0], tcz = tshz[m0];
            int mreg = m0;
#pragma unroll
            for (int k = 0; k < 8; ++k) {
                int mn = m0 + ((k + 1) & 7) * 64;   // next-iter prefetch (wraps)
                float tnx = tshx[mn], tny = tshy[mn], tnz = tshz[mn];
                float htn = 0.5f * (tcx * tcx + tcy * tcy + tcz * tcz);
                float tx = tcx, ty = tcy, tz = tcz;
#define PAIR(i) { float s = fmaf(px##i, tx, fmaf(py##i, ty, fmaf(pz##i, tz, -htn))); \
                if (s > bs##i) { bs##i = s; ix##i = mreg; } }
                FOR16(PAIR)
#undef PAIR
                mreg += 64;
                tcx = tnx; tcy = tny; tcz = tnz;
            }

            // wave argmax via order-preserving packed key: score hi-20 | (4095-m)
#define REDKEY(i) { unsigned ub = __float_as_uint(bs##i); \
            unsigned u = ((int)ub >= 0) ? (ub | 0x80000000u) : ~ub; \
            unsigned key = (u & 0xFFFFF000u) | (4095u - (unsigned)ix##i); \
            for (int off = 32; off; off >>= 1) { \
                unsigned o = (unsigned)__shfl_xor((int)key, off); \
                key = key > o ? key : o; } \
            if (lane == 0) keys[w][i] = key; }
            FOR16(REDKEY)
#undef REDKEY
            __syncthreads();

            if (tid < 16) {
                unsigned key = keys[0][tid];
#pragma unroll
                for (int ww = 1; ww < 8; ++ww) {
                    unsigned o = keys[ww][tid];
                    key = key > o ? key : o;
                }
                int m = 4095 - (int)(key & 0xFFFu);
                float qx2 = tshx[m], qy2 = tshy[m], qz2 = tshz[m];
                float x = spx[np + tid], y = spy[np + tid], z = spz[np + tid];
                float px = fmaf(R00, x, fmaf(R01, y, fmaf(R02, z, t0)));
                float py = fmaf(R10, x, fmaf(R11, y, fmaf(R12, z, t1)));
                float pz = fmaf(R20, x, fmaf(R21, y, fmaf(R22, z, t2)));
                float dx = px - qx2, dy = py - qy2, dz = pz - qz2;
                float dist = sqrtf(dx * dx + dy * dy + dz * dz);
                red[tid][0] = px; red[tid][1] = py; red[tid][2] = pz;
                red[tid][3] = qx2; red[tid][4] = qy2; red[tid][5] = qz2;
                red[tid][6] = px * qx2;  red[tid][7] = px * qy2;  red[tid][8] = px * qz2;
                red[tid][9] = py * qx2;  red[tid][10] = py * qy2; red[tid][11] = py * qz2;
                red[tid][12] = pz * qx2; red[tid][13] = pz * qy2; red[tid][14] = pz * qz2;
                red[tid][15] = dist;
            }
            __syncthreads();
            if (tid < 16) {
                float s = 0.f;
#pragma unroll
                for (int r = 0; r < 16; ++r) s += red[r][tid];
                sacc += s;
            }
            __syncthreads();   // keys/red reused next pass
        }

        // publish own slot (the store IS the arrival signal)
        if (tid < 16) {
            __hip_atomic_store(&acc[((size_t)step * NBLK + bid) * 16 + tid], sacc,
                               __ATOMIC_RELAXED, __HIP_MEMORY_SCOPE_AGENT);
        }

        // ---- sentinel poll-gather (no barrier, no counters) ----
        const unsigned* accu = (const unsigned*)(acc) + (size_t)step * NBLK * 16;
        {
            // own batch: 128 slots x 16 words; thread t polls 4 words
            int s = tid >> 2, w0 = (tid & 3) * 4;
            const unsigned* base = accu + ((size_t)(b * 128 + s)) * 16 + w0;
#pragma unroll
            for (int j = 0; j < 4; ++j) gd[w0 + j][s] = poll_word(base + j);
        }
        if (tid < 128) {        // batch-0 dist sums (for cross-batch conv)
            e0[tid] = poll_word(accu + (size_t)tid * 16 + 15);
        } else if (tid < 256) { // batch-1 dist sums
            int t2 = tid - 128;
            e1[t2] = poll_word(accu + (size_t)(128 + t2) * 16 + 15);
        }
        __syncthreads();

        // ---- fixed-order reduce (identical in every block) ----
        if (tid < 64) {
            int part = tid >> 4, c = tid & 15;
            float s = 0.f;
#pragma unroll
            for (int i = 0; i < 32; ++i) s += gd[c][part * 32 + i];
            gp[part][c] = s;
        } else if (tid < 96) {
            int j = tid - 64;
            ep0[j] = e0[4*j] + e0[4*j+1] + e0[4*j+2] + e0[4*j+3];
        } else if (tid < 128) {
            int j = tid - 96;
            ep1[j] = e1[4*j] + e1[4*j+1] + e1[4*j+2] + e1[4*j+3];
        }
        __syncthreads();
        if (tid < 16) asum[tid] = gp[0][tid] + gp[1][tid] + gp[2][tid] + gp[3][tid];
        __syncthreads();

        // ---- redundant per-block solve (bit-identical across blocks) ----
        if (tid == 0) {
            float err0 = 0.f, err1 = 0.f;
            for (int j = 0; j < 32; ++j) err0 += ep0[j];
            for (int j = 0; j < 32; ++j) err1 += ep1[j];
            err0 *= (1.f / NPTS);
            err1 *= (1.f / NPTS);
            bool conv = (fabsf(err0 - st_err[0]) < ICP_TOL) &&
                        (fabsf(err1 - st_err[1]) < ICP_TOL);
            int dn = (doneLDS && step > 0) ? 1 : 0;   // latched (LDS persists)
            dn = (step == 0) ? (conv ? 1 : 0) : (dn || conv);
            if (!dn) {
                float a[16];
                for (int i = 0; i < 16; ++i) a[i] = asum[i];
                const float inv_n = 1.f / NPTS;
                float pmx = a[0]*inv_n, pmy = a[1]*inv_n, pmz = a[2]*inv_n;
                float qmx = a[3]*inv_n, qmy = a[4]*inv_n, qmz = a[5]*inv_n;
                float H[3][3];
                for (int i = 0; i < 3; ++i)
                    for (int j = 0; j < 3; ++j)
                        H[i][j] = a[6 + 3*i + j] - a[i]*a[3 + j]*inv_n;
                float Sxx=H[0][0], Sxy=H[0][1], Sxz=H[0][2];
                float Syx=H[1][0], Syy=H[1][1], Syz=H[1][2];
                float Szx=H[2][0], Szy=H[2][1], Szz=H[2][2];
                float Nm[4][4];
                Nm[0][0] = Sxx+Syy+Szz; Nm[0][1] = Syz-Szy;
                Nm[0][2] = Szx-Sxz;     Nm[0][3] = Sxy-Syx;
                Nm[1][1] = Sxx-Syy-Szz; Nm[1][2] = Sxy+Syx; Nm[1][3] = Szx+Sxz;
                Nm[2][2] = -Sxx+Syy-Szz; Nm[2][3] = Syz+Szy;
                Nm[3][3] = -Sxx-Syy+Szz;
                Nm[1][0]=Nm[0][1]; Nm[2][0]=Nm[0][2]; Nm[3][0]=Nm[0][3];
                Nm[2][1]=Nm[1][2]; Nm[3][1]=Nm[1][3]; Nm[3][2]=Nm[2][3];
                float qv[4];
                horn_quat(Nm, qv);
                float qw = qv[0], qx = qv[1], qy = qv[2], qz = qv[3];
                float R00n = 1.f - 2.f*(qy*qy + qz*qz);
                float R01n = 2.f*(qx*qy - qw*qz);
                float R02n = 2.f*(qx*qz + qw*qy);
                float R10n = 2.f*(qx*qy + qw*qz);
                float R11n = 1.f - 2.f*(qx*qx + qz*qz);
                float R12n = 2.f*(qy*qz - qw*qx);
                float R20n = 2.f*(qx*qz - qw*qy);
                float R21n = 2.f*(qy*qz + qw*qx);
                float R22n = 1.f - 2.f*(qx*qx + qy*qy);
                float tx = qmx - (R00n*pmx + R01n*pmy + R02n*pmz);
                float ty = qmy - (R10n*pmx + R11n*pmy + R12n*pmz);
                float tz = qmz - (R20n*pmx + R21n*pmy + R22n*pmz);
                float C00=stq[0], C01=stq[1], C02=stq[2];
                float C10=stq[3], C11=stq[4], C12=stq[5];
                float C20=stq[6], C21=stq[7], C22=stq[8];
                float T0=stq[9], T1=stq[10], T2=stq[11];
                float ns[12];
                ns[0] = R00n*C00 + R01n*C10 + R02n*C20;
                ns[1] = R00n*C01 + R01n*C11 + R02n*C21;
                ns[2] = R00n*C02 + R01n*C12 + R02n*C22;
                ns[3] = R10n*C00 + R11n*C10 + R12n*C20;
                ns[4] = R10n*C01 + R11n*C11 + R12n*C21;
                ns[5] = R10n*C02 + R11n*C12 + R12n*C22;
                ns[6] = R20n*C00 + R21n*C10 + R22n*C20;
                ns[7] = R20n*C01 + R21n*C11 + R22n*C21;
                ns[8] = R20n*C02 + R21n*C12 + R22n*C22;
                ns[9]  = R00n*T0 + R01n*T1 + R02n*T2 + tx;
                ns[10] = R10n*T0 + R11n*T1 + R12n*T2 + ty;
                ns[11] = R20n*T0 + R21n*T1 + R22n*T2 + tz;
                for (int i = 0; i < 12; ++i) stq[i] = ns[i];
                st_err[0] = err0;
                st_err[1] = err1;
            }
            doneLDS = dn;
        }
        __syncthreads();
        if (doneLDS) break;   // bit-identical across all blocks
    }

    if ((bid == 0 || bid == 128) && tid == 0) {
        float r00 = stq[0], r01 = stq[1], r02 = stq[2];
        float r10 = stq[3], r11 = stq[4], r12 = stq[5];
        float r20 = stq[6], r21 = stq[7], r22 = stq[8];
        float qw = 0.5f * sqrtf(fmaxf(1.f + r00 + r11 + r22, 1e-12f));
        float qx = 0.5f * sqrtf(fmaxf(1.f + r00 - r11 - r22, 1e-12f));
        float qy = 0.5f * sqrtf(fmaxf(1.f - r00 + r11 - r22, 1e-12f));
        float qz = 0.5f * sqrtf(fmaxf(1.f - r00 - r11 + r22, 1e-12f));
        qx = (r21 - r12 >= 0.f) ? qx : -qx;
        qy = (r02 - r20 >= 0.f) ? qy : -qy;
        qz = (r10 - r01 >= 0.f) ? qz : -qz;
        out[b * 7 + 0] = stq[9];
        out[b * 7 + 1] = stq[10];
        out[b * 7 + 2] = stq[11];
        out[b * 7 + 3] = qx;
        out[b * 7 + 4] = qy;
        out[b * 7 + 5] = qz;
        out[b * 7 + 6] = qw;
    }
}

extern "C" void kernel_launch(void* const* d_in, const int* in_sizes, int n_in,
                              void* d_out, int out_size, void* d_ws, size_t ws_size,
                              hipStream_t stream) {
    const float* psrc = (const float*)d_in[0];
    const float* ptgt = (const float*)d_in[1];
    float* out = (float*)d_out;
    float* ws = (float*)d_ws;

    init_kernel<<<32, 256, 0, stream>>>(ptgt, ws);
    icp_main<<<NBLK, 512, 0, stream>>>(psrc, ws, out);
}